// Round 6
// baseline (39.887 us; speedup 1.0000x reference)
//
#include <hip/hip_runtime.h>

#define TPB  256
#define FPC  30
// Each thread owns 2 consecutive cells: 60 floats = 240 B = 15 aligned float4
// per input. 30 dwordx4 loads issued back-to-back (sched_barrier pins them),
// ~30 KB in flight per wave, no LDS tile, no barriers, no DMA drain cycle.

__launch_bounds__(TPB)
__global__ void yolo_loss_kernel(const float* __restrict__ bb,
                                 const float* __restrict__ gt,
                                 float* __restrict__ ws,
                                 int npairs, int nblocks) {
    __shared__ float sRed[TPB / 64][6];

    const int tid  = threadIdx.x;
    const int pair = blockIdx.x * TPB + tid;

    float L = 0.f, Lc = 0.f, Lconf = 0.f, Lcls = 0.f, Isum = 0.f, On = 0.f;

    if (pair < npairs) {
        const float4* __restrict__ b4 = (const float4*)bb + (size_t)pair * 15;
        const float4* __restrict__ g4 = (const float4*)gt + (size_t)pair * 15;

        float4 rb[15], rg[15];
#pragma unroll
        for (int j = 0; j < 15; ++j) rb[j] = b4[j];
#pragma unroll
        for (int j = 0; j < 15; ++j) rg[j] = g4[j];
        __builtin_amdgcn_sched_barrier(0);   // loads stay above: all 30 in flight

        float fb[60], fg[60];
#pragma unroll
        for (int j = 0; j < 15; ++j) {
            fb[4*j+0] = rb[j].x; fb[4*j+1] = rb[j].y;
            fb[4*j+2] = rb[j].z; fb[4*j+3] = rb[j].w;
            fg[4*j+0] = rg[j].x; fg[4*j+1] = rg[j].y;
            fg[4*j+2] = rg[j].z; fg[4*j+3] = rg[j].w;
        }

        // OFF is a literal (0 or 30) -> all fb/fg indices compile-time constant.
#define DO_CELL(OFF, CELL)                                                     \
        do {                                                                   \
            const int   w  = (CELL) % 49;                                      \
            const float gx = (float)(w % 7) * 64.0f;                           \
            const float gy = (float)(w / 7) * 64.0f;                           \
            const float g0 = fg[(OFF)+5], g1 = fg[(OFF)+6];                    \
            const float g2 = fg[(OFF)+7], g3 = fg[(OFF)+8];                    \
            const float g_area = (g2 - g0) * (g3 - g1);                        \
            const float b1x = fb[(OFF)+0], b1y = fb[(OFF)+1];                  \
            const float b1w = fb[(OFF)+2], b1h = fb[(OFF)+3];                  \
            const float b1c = fb[(OFF)+4];                                     \
            const float b2x = fb[(OFF)+5], b2y = fb[(OFF)+6];                  \
            const float b2w = fb[(OFF)+7], b2h = fb[(OFF)+8];                  \
            const float b2c = fb[(OFF)+9];                                     \
            auto iou_of = [&](float bx, float by, float bw, float bh) {        \
                float px = truncf(gx + bx * 64.0f);                            \
                float py = truncf(gy + by * 64.0f);                            \
                float pw = truncf(bw * 448.0f);                                \
                float ph = truncf(bh * 448.0f);                                \
                float x1 = fmaxf(0.0f,   px - pw * 0.5f);                      \
                float y1 = fmaxf(0.0f,   py - ph * 0.5f);                      \
                float x2 = fminf(447.0f, px + pw * 0.5f);                      \
                float y2 = fminf(447.0f, py + ph * 0.5f);                      \
                float parea = (x2 - x1) * (y2 - y1);                           \
                float lx = fmaxf(x1, g0), rx = fminf(x2, g2);                  \
                float uy = fmaxf(y1, g1), dn = fminf(y2, g3);                  \
                float inter = (rx - lx) * (dn - uy);                           \
                float denom = parea + g_area - inter;                          \
                denom = (denom == 0.0f) ? 1.0f : denom;                        \
                return ((rx >= lx) && (dn >= uy)) ? (inter / denom) : 0.0f;    \
            };                                                                 \
            const float iou1 = iou_of(b1x, b1y, b1w, b1h);                     \
            const float iou2 = iou_of(b2x, b2y, b2w, b2h);                     \
            const bool  p1   = iou1 > iou2;                                    \
            const float pbx = p1 ? b1x : b2x, pby = p1 ? b1y : b2y;            \
            const float pbw = p1 ? b1w : b2w, pbh = p1 ? b1h : b2h;            \
            const float pbc = p1 ? b1c : b2c;                                  \
            const float npc = p1 ? b2c : b1c;                                  \
            const float iousel = p1 ? iou1 : iou2;                             \
            const bool obj = (rintf(fg[(OFF)+9]) != 0.0f);                     \
            const float dx = fg[(OFF)+0] - pbx;                                \
            const float dy = fg[(OFF)+1] - pby;                                \
            const float dw = sqrtf(fg[(OFF)+2] + 1e-8f) - sqrtf(pbw + 1e-8f);  \
            const float dh = sqrtf(fg[(OFF)+3] + 1e-8f) - sqrtf(pbh + 1e-8f);  \
            const float coord = 5.0f * (dx*dx + dy*dy + dw*dw + dh*dh);        \
            float confobj = pbc - iousel; confobj *= confobj;                  \
            float cls = 0.f;                                                   \
            _Pragma("unroll")                                                  \
            for (int k = 0; k < 20; ++k) {                                     \
                float d = fg[(OFF)+10+k] - fb[(OFF)+10+k];                     \
                cls += d * d;                                                  \
            }                                                                  \
            cls *= (1.0f / 20.0f);                                             \
            const float noobj_of_obj = 0.5f * npc * npc;                       \
            const float objloss   = coord + confobj + cls + noobj_of_obj;      \
            const float noobjloss = 0.5f * b1c * b1c + b2c * b2c;              \
            if (obj) {                                                         \
                L += objloss; Lc += coord; Lconf += confobj + npc * npc;       \
                Lcls += cls;  Isum += iousel; On += 1.0f;                      \
            } else {                                                           \
                L += noobjloss; Lconf += noobjloss;                            \
            }                                                                  \
        } while (0)

        const int c0 = pair * 2;
        DO_CELL(0,  c0);
        DO_CELL(30, c0 + 1);
#undef DO_CELL
    }

    // ---- Reduction: wave shuffle -> LDS -> ONE partial store per block -----
    float v[6] = {L, Lc, Lconf, Lcls, Isum, On};
#pragma unroll
    for (int k = 0; k < 6; ++k) {
#pragma unroll
        for (int off = 32; off > 0; off >>= 1)
            v[k] += __shfl_down(v[k], off, 64);
    }
    const int wave = tid >> 6;
    const int lane = tid & 63;
    if (lane == 0) {
#pragma unroll
        for (int k = 0; k < 6; ++k) sRed[wave][k] = v[k];
    }
    __syncthreads();
    if (tid == 0) {
#pragma unroll
        for (int k = 0; k < 6; ++k) {
            float s = sRed[0][k] + sRed[1][k] + sRed[2][k] + sRed[3][k];
            ws[k * nblocks + blockIdx.x] = s;   // plain store, no atomics
        }
    }
}

// Second stage: 6 blocks, one per output scalar; each reduces nblocks partials.
__global__ void reduce_partials(const float* __restrict__ ws,
                                float* __restrict__ out, int nblocks) {
    __shared__ float sw[4];
    const int k = blockIdx.x;
    float s = 0.f;
    for (int i = threadIdx.x; i < nblocks; i += blockDim.x)
        s += ws[k * nblocks + i];
#pragma unroll
    for (int off = 32; off > 0; off >>= 1)
        s += __shfl_down(s, off, 64);
    if ((threadIdx.x & 63) == 0) sw[threadIdx.x >> 6] = s;
    __syncthreads();
    if (threadIdx.x == 0) out[k] = sw[0] + sw[1] + sw[2] + sw[3];
}

extern "C" void kernel_launch(void* const* d_in, const int* in_sizes, int n_in,
                              void* d_out, int out_size, void* d_ws, size_t ws_size,
                              hipStream_t stream) {
    const float* bb = (const float*)d_in[0];
    const float* gt = (const float*)d_in[1];
    float* out = (float*)d_out;
    float* ws  = (float*)d_ws;

    const int ncells = in_sizes[0] / FPC;             // 802816
    const int npairs = ncells / 2;                    // 401408 (even)
    const int grid   = (npairs + TPB - 1) / TPB;      // 1568

    yolo_loss_kernel<<<grid, TPB, 0, stream>>>(bb, gt, ws, npairs, grid);
    reduce_partials<<<6, 256, 0, stream>>>(ws, out, grid);
}

// Round 7
// 36.115 us; speedup vs baseline: 1.1045x; 1.1045x over previous
//
#include <hip/hip_runtime.h>

#define TPB    64              // 1 wave per block
#define CELLS  64              // 1 cell per thread
#define FPC    30
#define TILE_F (CELLS * FPC)   // 1920 floats = 7680 B per input per tile

typedef const __attribute__((address_space(1))) void* gptr_t;
typedef __attribute__((address_space(3))) void* lptr_t;

// 8 DMA chunks of 1 KiB per input; chunk 7 starts at byte 6656 so it ends
// exactly at 7680 (overlaps chunk 6 by 512 B with identical data -> safe,
// and never reads past the tile / array end).

__launch_bounds__(TPB)
__global__ void yolo_loss_kernel(const float* __restrict__ bb,
                                 const float* __restrict__ gt,
                                 float* __restrict__ ws,
                                 int nblocks) {
    __shared__ float sBB[TILE_F];
    __shared__ float sGT[TILE_F];

    const int tid = threadIdx.x;          // == lane (single wave)
    const int bid = blockIdx.x;

    const float* __restrict__ bsrc = bb + (size_t)bid * TILE_F;
    const float* __restrict__ gsrc = gt + (size_t)bid * TILE_F;

#pragma unroll
    for (int c = 0; c < 8; ++c) {
        const int of = (c < 7) ? c * 256 : 1664;     // float offset of chunk
        __builtin_amdgcn_global_load_lds((gptr_t)(bsrc + of + tid * 4),
                                         (lptr_t)(&sBB[of]), 16, 0, 0);
        __builtin_amdgcn_global_load_lds((gptr_t)(gsrc + of + tid * 4),
                                         (lptr_t)(&sGT[of]), 16, 0, 0);
    }
    __syncthreads();   // vmcnt(0) drain; 16 chunks were in flight

    // ---- Per-cell compute --------------------------------------------------
    const float* __restrict__ Bp = &sBB[tid * FPC];
    const float* __restrict__ Gp = &sGT[tid * FPC];

    const int cell = bid * CELLS + tid;
    const int w = cell % 49;
    const float gx = (float)(w % 7) * 64.0f;
    const float gy = (float)(w / 7) * 64.0f;

    const float g0 = Gp[5], g1 = Gp[6], g2 = Gp[7], g3 = Gp[8];
    const float g_area = (g2 - g0) * (g3 - g1);

    const float b1x = Bp[0], b1y = Bp[1], b1w = Bp[2], b1h = Bp[3], b1c = Bp[4];
    const float b2x = Bp[5], b2y = Bp[6], b2w = Bp[7], b2h = Bp[8], b2c = Bp[9];

    auto iou_of = [&](float bx, float by, float bw, float bh) -> float {
        float px = truncf(gx + bx * 64.0f);
        float py = truncf(gy + by * 64.0f);
        float pw = truncf(bw * 448.0f);
        float ph = truncf(bh * 448.0f);
        float x1 = fmaxf(0.0f,   px - pw * 0.5f);
        float y1 = fmaxf(0.0f,   py - ph * 0.5f);
        float x2 = fminf(447.0f, px + pw * 0.5f);
        float y2 = fminf(447.0f, py + ph * 0.5f);
        float parea = (x2 - x1) * (y2 - y1);
        float lx = fmaxf(x1, g0), rx = fminf(x2, g2);
        float uy = fmaxf(y1, g1), dn = fminf(y2, g3);
        float inter = (rx - lx) * (dn - uy);
        float denom = parea + g_area - inter;
        denom = (denom == 0.0f) ? 1.0f : denom;
        return ((rx >= lx) && (dn >= uy)) ? (inter / denom) : 0.0f;
    };

    const float iou1 = iou_of(b1x, b1y, b1w, b1h);
    const float iou2 = iou_of(b2x, b2y, b2w, b2h);
    const bool  p1   = iou1 > iou2;

    const float pbx = p1 ? b1x : b2x, pby = p1 ? b1y : b2y;
    const float pbw = p1 ? b1w : b2w, pbh = p1 ? b1h : b2h;
    const float pbc = p1 ? b1c : b2c;
    const float npc = p1 ? b2c : b1c;
    const float iousel = p1 ? iou1 : iou2;

    const bool obj = (rintf(Gp[9]) != 0.0f);   // jnp.round: half-to-even

    const float dx = Gp[0] - pbx;
    const float dy = Gp[1] - pby;
    const float dw = sqrtf(Gp[2] + 1e-8f) - sqrtf(pbw + 1e-8f);
    const float dh = sqrtf(Gp[3] + 1e-8f) - sqrtf(pbh + 1e-8f);
    const float coord = 5.0f * (dx * dx + dy * dy + dw * dw + dh * dh);

    float confobj = pbc - iousel;
    confobj *= confobj;

    float cls = 0.f;
#pragma unroll
    for (int k = 0; k < 20; ++k) {
        float d = Gp[10 + k] - Bp[10 + k];
        cls += d * d;
    }
    cls *= (1.0f / 20.0f);

    const float noobj_of_obj = 0.5f * npc * npc;
    const float objloss   = coord + confobj + cls + noobj_of_obj;
    const float noobjloss = 0.5f * b1c * b1c + b2c * b2c;

    float L, Lc, Lconf, Lcls, Isum, On;
    if (obj) {
        L = objloss; Lc = coord; Lconf = confobj + npc * npc;
        Lcls = cls;  Isum = iousel; On = 1.0f;
    } else {
        L = noobjloss; Lc = 0.f; Lconf = noobjloss; Lcls = 0.f; Isum = 0.f; On = 0.f;
    }

    // ---- Single-wave reduction: shuffle only, lane0 stores 6 partials ------
    float v[6] = {L, Lc, Lconf, Lcls, Isum, On};
#pragma unroll
    for (int k = 0; k < 6; ++k) {
#pragma unroll
        for (int off = 32; off > 0; off >>= 1)
            v[k] += __shfl_down(v[k], off, 64);
    }
    if (tid == 0) {
#pragma unroll
        for (int k = 0; k < 6; ++k)
            ws[(size_t)k * nblocks + bid] = v[k];
    }
}

// Second stage: 6 blocks x 1024 threads, float4 loads (nblocks % 4 == 0).
__global__ void reduce_partials(const float* __restrict__ ws,
                                float* __restrict__ out, int nblocks) {
    __shared__ float sw[16];
    const int k   = blockIdx.x;
    const int tid = threadIdx.x;
    const float4* __restrict__ w4 = (const float4*)(ws + (size_t)k * nblocks);
    const int nf4 = nblocks >> 2;                 // 12544/4 = 3136

    float s = 0.f;
    for (int i = tid; i < nf4; i += blockDim.x) {
        float4 q = w4[i];
        s += (q.x + q.y) + (q.z + q.w);
    }
#pragma unroll
    for (int off = 32; off > 0; off >>= 1)
        s += __shfl_down(s, off, 64);
    if ((tid & 63) == 0) sw[tid >> 6] = s;
    __syncthreads();
    if (tid == 0) {
        float t = 0.f;
#pragma unroll
        for (int j = 0; j < 16; ++j) t += sw[j];
        out[k] = t;
    }
}

extern "C" void kernel_launch(void* const* d_in, const int* in_sizes, int n_in,
                              void* d_out, int out_size, void* d_ws, size_t ws_size,
                              hipStream_t stream) {
    const float* bb = (const float*)d_in[0];
    const float* gt = (const float*)d_in[1];
    float* out = (float*)d_out;
    float* ws  = (float*)d_ws;

    const int ncells = in_sizes[0] / FPC;   // 802816
    const int grid   = ncells / CELLS;      // 12544 (exact)

    yolo_loss_kernel<<<grid, TPB, 0, stream>>>(bb, gt, ws, grid);
    reduce_partials<<<6, 1024, 0, stream>>>(ws, out, grid);
}